// Round 12
// baseline (1956.558 us; speedup 1.0000x reference)
//
#include <hip/hip_runtime.h>

// ws layout (bytes):
//   [0, 33554432)            M as double, 256 blocks x 16384 (131072 B each).
//                            After k_svd, first 65536 B of each block's slot is
//                            overwritten with T as float (16384 floats).
//   [33554432, 34603008)     GEMM partials: 8 * 256 * 128 floats

#define NSTR 132               // double stride for 128-row columns in LDS (EVEN: 16B-aligned double2)
// float-phase offsets (in floats) inside the shared pool
#define U32_OFF 0
#define V32_OFF 8448
#define RA_OFF  16896
#define RB_OFF  25344
#define WF_OFF  33792
#define POOL_BYTES 151552      // 37888 floats; double phase needs 128*132*8 = 135168 B

// zero-cost fence (validated R2/R3): orders DS ops across sub-rounds within a
// wave; HW DS pipe is in-order per wave, so a compile-time fence suffices.
#define WAVE_FENCE() do { __asm__ __volatile__("" ::: "memory"); \
                          __builtin_amdgcn_wave_barrier();        \
                          __asm__ __volatile__("" ::: "memory"); } while (0)

// DPP lane-permute on a double (2x update_dpp on the 32-bit halves). VALU-pipe
// (~2cy/op) vs ds_bpermute (~40cy LDS-pipe) — used for intra-8-lane reduces.
template<int CTRL>
__device__ __forceinline__ double dpp_d(double x) {
    union { double d; int i[2]; } u, r;
    u.d = x;
    r.i[0] = __builtin_amdgcn_update_dpp(0, u.i[0], CTRL, 0xF, 0xF, true);
    r.i[1] = __builtin_amdgcn_update_dpp(0, u.i[1], CTRL, 0xF, 0xF, true);
    return r.d;
}
// sum over the 8 lanes of a slot (lanes 8-aligned): xor1 (quad_perm [1,0,3,2]),
// xor2 (quad_perm [2,3,0,1]), cross-quad (row_half_mirror). All-VALU.
// Validated R7/R10: leaves the identical slot-sum in ALL 8 lanes.
__device__ __forceinline__ double slot8_sum(double g) {
    g += dpp_d<0xB1>(g);
    g += dpp_d<0x4E>(g);
    g += dpp_d<0x141>(g);
    return g;
}

// Fast-Givens rotation parameters (R12). Inputs: true d_=beta-alpha, g_=gamma.
// Outputs: tt (tan, fp32-level — validated angle tolerance), cc (fp64 Newton:
// consistent with tt so the effective rotation [[c,-ct],[ct,c]] is orthogonal
// to 1e-14), seff = c*t, rc = 1/c (exact identity 1/c = c*(1+t^2)).
#define ROT_FG(d_, g_, tt_, cc_, se_, rc_) do {                           \
    float d32 = (float)(d_), g32 = (float)(g_);                           \
    float h32 = sqrtf(fmaf(d32, d32, 4.0f*g32*g32));                      \
    float den = d32 + copysignf(h32, d32);                                \
    float t32 = __fdividef(2.0f*g32, den);                                \
    tt_ = (double)t32;                                                    \
    double opt2_ = fma(tt_, tt_, 1.0);                                    \
    double c0_ = (double)rsqrtf(fmaf(t32, t32, 1.0f));                    \
    cc_ = c0_*0.5*(3.0 - c0_*c0_*opt2_);                                 \
    rc_ = cc_*opt2_;                                                      \
    se_ = cc_*tt_;                                                        \
} while (0)

// ---------------- Stage 1: features + conv chain -> M (fp64) ----------------
__global__ __launch_bounds__(256) void k_feat(const float* __restrict__ obs,
        const float* __restrict__ c1w, const float* __restrict__ c1b,
        const float* __restrict__ c2w, const float* __restrict__ c2b,
        double* __restrict__ M)
{
    __shared__ __align__(16) float lds[256*29];
    const int t = threadIdx.x;
    const float4* obs4 = (const float4*)obs;
    float4* lds4 = (float4*)lds;
    const size_t base4 = (size_t)blockIdx.x * 1856;
    for (int idx = t; idx < 1856; idx += 256) lds4[idx] = obs4[base4 + idx];
    __syncthreads();
    const float* o = &lds[t*29];
    double f0=0,f1=0,f2=0,f3=0,f4=0,f5=0;
    #pragma unroll
    for (int d=1; d<5; ++d) f0 += (double)o[d]*d;
    #pragma unroll
    for (int d=1; d<5; ++d) f1 += (double)o[5+d]*d;
    f2 = (double)o[11] + 2.0*(double)o[12];
    #pragma unroll
    for (int d=1; d<8; ++d) f3 += (double)o[13+d]*d;
    #pragma unroll
    for (int d=1; d<6; ++d) f4 += (double)o[21+d]*d;
    f5 = (double)o[28];
    const double w0=c1w[0], w1=c1w[1], w2=c1w[2], w3=c1w[3], b1=c1b[0];
    const double cw0=c2w[0], cw1=c2w[1], b2=c2b[0];
    // conv1 stride2 pad2 k4: 6 -> 4 -> 3 -> 2 ; conv2 k2: -> 1
    double y0 = b1 + f0*w2 + f1*w3;
    double y1 = b1 + f0*w0 + f1*w1 + f2*w2 + f3*w3;
    double y2 = b1 + f2*w0 + f3*w1 + f4*w2 + f5*w3;
    double y3 = b1 + f4*w0 + f5*w1;
    double z0 = b1 + y0*w2 + y1*w3;
    double z1 = b1 + y0*w0 + y1*w1 + y2*w2 + y3*w3;
    double z2 = b1 + y2*w0 + y3*w1;
    double u0 = b1 + z0*w2 + z1*w3;
    double u1 = b1 + z0*w0 + z1*w1 + z2*w2;
    double m  = b2 + u0*cw0 + u1*cw1;
    M[(size_t)blockIdx.x*256 + t] = m;
}

// ---------------- Stage 2: per-batch SVD + QR signs + MLP + T ----------------
__global__ __launch_bounds__(512, 2) void k_svd(
        const float* __restrict__ w1g, const float* __restrict__ w2g,
        double* __restrict__ wsM)
{
    __shared__ __align__(16) char smem[POOL_BYTES];
    double* Ad = (double*)smem;
    float*  Af = (float*)smem;
    __shared__ double colnorm[128];   // TRUE column norms^2 (scale-folded)
    __shared__ double dcol[128];      // fast-Givens scale d per column
    __shared__ double invdcol[128];   // 1/d per column (angle-level accuracy)
    __shared__ double sig_d[128];
    __shared__ double sigs_d[64];
    __shared__ float  sigf[64];
    __shared__ double tau2[2][64];
    __shared__ double vjs2[2][64];
    __shared__ int    perm[128];
    __shared__ int    redflag[8];
    __shared__ int    convflag;

    const int t = threadIdx.x;
    const int b = blockIdx.x;
    double* Mg = wsM + (size_t)b*16384;

    const int wv   = t >> 6;       // wave 0..7
    const int lk   = t & 63;       // lane in wave
    const int slot = lk >> 3;      // pair slot 0..7
    const int sub  = lk & 7;       // lane in slot

    // load M column-major into LDS (fp64)
    for (int idx = t; idx < 16384; idx += 512) {
        int r = idx >> 7, c = idx & 127;
        Ad[c*NSTR + r] = Mg[idx];
    }
    __syncthreads();

    // ---- initial column norms ----
    {
        const int gs = t >> 3;     // global slot 0..63
        #pragma unroll
        for (int h = 0; h < 2; ++h) {
            const int c = gs + 64*h;
            const double2* P = (const double2*)&Ad[c*NSTR + 2*sub];
            double sacc = 0.0;
            #pragma unroll
            for (int m = 0; m < 8; ++m) {
                double2 v = P[m*8];
                sacc = fma(v.x, v.x, sacc); sacc = fma(v.y, v.y, sacc);
            }
            sacc = slot8_sum(sacc);
            if (sub == 0) colnorm[c] = sacc;
        }
    }
    __syncthreads();

    // ---- de Rijk pre-sort: permute columns by descending norm (full 128
    // columns: i<32, 16384 elems — the R8/R9 bug was i<16) ----
    if (t < 128) {
        double my = colnorm[t]; int rk = 0;
        for (int c2 = 0; c2 < 128; ++c2) {
            double v = colnorm[c2];
            rk += (v > my) || (v == my && c2 < t);
        }
        perm[rk] = t;
    }
    __syncthreads();
    {
        double tmp[32]; double cn = 0.0;
        #pragma unroll
        for (int i = 0; i < 32; ++i) {
            int idx = t + i*512; int k = idx >> 7, r = idx & 127;
            tmp[i] = Ad[perm[k]*NSTR + r];
        }
        if (t < 128) cn = colnorm[perm[t]];
        __syncthreads();
        #pragma unroll
        for (int i = 0; i < 32; ++i) {
            int idx = t + i*512; int k = idx >> 7, r = idx & 127;
            Ad[k*NSTR + r] = tmp[i];
        }
        if (t < 128) { colnorm[t] = cn; dcol[t] = 1.0; invdcol[t] = 1.0; }
    }
    __syncthreads();

    // ---- hierarchical one-sided Jacobi, fp64, FAST-GIVENS (A = b*d) ----
    // Rotation: b_p' = b_p - ar*b_q ; b_q' = b_q + br*b_p (ONE FMA/elem),
    // ar = t*dq/dp, br = t*dp/dq, d' = c*d. Effective rotation = exact
    // Givens(c, c*t); colnorm tracks TRUE norms. Threshold gate at 1e-20.
    for (int sweep = 0; sweep < 16; ++sweep) {
        // fold scales into data every 4 sweeps (d decays <= 2^-64/sweep)
        if (sweep && (sweep & 3) == 0) {
            for (int idx = t; idx < 16384; idx += 512) {
                int r = idx >> 7, c = idx & 127;
                Ad[c*NSTR + r] *= dcol[c];
            }
            __syncthreads();
            if (t < 128) { dcol[t] = 1.0; invdcol[t] = 1.0; }
            __syncthreads();
        }
        int big = 0;

        // ---- internal phase: wave wv owns cols 16wv..16wv+15 ----
        // Norms+scales ride in registers; partner values via DPP/shfl.
        {
            const int ca = 16*wv + slot, cb = ca + 8;
            double2* PA = (double2*)&Ad[ca*NSTR + 2*sub];
            double2* PB = (double2*)&Ad[cb*NSTR + 2*sub];
            double2 a8[8], b8[8];
            #pragma unroll
            for (int m = 0; m < 8; ++m) { a8[m] = PA[m*8]; b8[m] = PB[m*8]; }
            double nA = colnorm[ca], nB = colnorm[cb];
            double dA = dcol[ca], iA = invdcol[ca];
            double dB = dcol[cb], iB = invdcol[cb];
            for (int s = 1; s < 8; ++s) {
                const int pa = 16*wv + (slot ^ s), pb = pa + 8;
                const int d8 = s << 3;
                const double2* QA = (const double2*)&Ad[pa*NSTR + 2*sub];
                const double2* QB = (const double2*)&Ad[pb*NSTR + 2*sub];
                double2 ya[8], yb[8];
                #pragma unroll
                for (int m = 0; m < 8; ++m) { ya[m] = QA[m*8]; yb[m] = QB[m*8]; }
                double nya, dya, iya, nyb, dyb, iyb;
                if (s == 1) {
                    nya = dpp_d<0x128>(nA); dya = dpp_d<0x128>(dA); iya = dpp_d<0x128>(iA);
                    nyb = dpp_d<0x128>(nB); dyb = dpp_d<0x128>(dB); iyb = dpp_d<0x128>(iB);
                } else {
                    nya = __shfl_xor(nA, d8); dya = __shfl_xor(dA, d8); iya = __shfl_xor(iA, d8);
                    nyb = __shfl_xor(nB, d8); dyb = __shfl_xor(dB, d8); iyb = __shfl_xor(iB, d8);
                }
                double gA0=0.0, gA1=0.0, gB0=0.0, gB1=0.0;
                #pragma unroll
                for (int m = 0; m < 4; ++m) {
                    gA0 = fma(a8[m].x, ya[m].x, gA0); gA0 = fma(a8[m].y, ya[m].y, gA0);
                    gB0 = fma(b8[m].x, yb[m].x, gB0); gB0 = fma(b8[m].y, yb[m].y, gB0);
                }
                #pragma unroll
                for (int m = 4; m < 8; ++m) {
                    gA1 = fma(a8[m].x, ya[m].x, gA1); gA1 = fma(a8[m].y, ya[m].y, gA1);
                    gB1 = fma(b8[m].x, yb[m].x, gB1); gB1 = fma(b8[m].y, yb[m].y, gB1);
                }
                double gA = slot8_sum(gA0 + gA1) * (dA*dya);   // TRUE gamma
                double gB = slot8_sum(gB0 + gB1) * (dB*dyb);
                const int pside = (slot < (slot ^ s));
                // --- A rotation ---
                {
                    double al = pside ? nA : nya, be = pside ? nya : nA;
                    double g2 = gA*gA, pr = al*be;
                    const bool rot = (g2 > pr*1e-20);
                    big |= rot;
                    if (__any(rot)) {
                        double tt, cc, se, rc; ROT_FG(be - al, gA, tt, cc, se, rc);
                        tt = rot ? tt : 0.0; cc = rot ? cc : 1.0;
                        se = rot ? se : 0.0; rc = rot ? rc : 1.0;
                        double coef = tt * dya * iA;
                        double sgn = pside ? -coef : coef;
                        #pragma unroll
                        for (int m = 0; m < 8; ++m) {
                            a8[m].x = fma(sgn, ya[m].x, a8[m].x);
                            a8[m].y = fma(sgn, ya[m].y, a8[m].y);
                        }
                        double cs2 = 2.0*cc*se*gA;
                        nA = pside ? fma(cc*cc, nA, fma(se*se, nya, -cs2))
                                   : fma(se*se, nya, fma(cc*cc, nA,  cs2));
                        dA *= cc; iA *= rc;
                        #pragma unroll
                        for (int m = 0; m < 8; ++m) PA[m*8] = a8[m];
                    }
                }
                // --- B rotation ---
                {
                    double al = pside ? nB : nyb, be = pside ? nyb : nB;
                    double g2 = gB*gB, pr = al*be;
                    const bool rot = (g2 > pr*1e-20);
                    big |= rot;
                    if (__any(rot)) {
                        double tt, cc, se, rc; ROT_FG(be - al, gB, tt, cc, se, rc);
                        tt = rot ? tt : 0.0; cc = rot ? cc : 1.0;
                        se = rot ? se : 0.0; rc = rot ? rc : 1.0;
                        double coef = tt * dyb * iB;
                        double sgn = pside ? -coef : coef;
                        #pragma unroll
                        for (int m = 0; m < 8; ++m) {
                            b8[m].x = fma(sgn, yb[m].x, b8[m].x);
                            b8[m].y = fma(sgn, yb[m].y, b8[m].y);
                        }
                        double cs2 = 2.0*cc*se*gB;
                        nB = pside ? fma(cc*cc, nB, fma(se*se, nyb, -cs2))
                                   : fma(se*se, nyb, fma(cc*cc, nB,  cs2));
                        dB *= cc; iB *= rc;
                        #pragma unroll
                        for (int m = 0; m < 8; ++m) PB[m*8] = b8[m];
                    }
                }
                WAVE_FENCE();
            }
            if (sub == 0) {
                colnorm[ca] = nA; colnorm[cb] = nB;
                dcol[ca] = dA; dcol[cb] = dB;
                invdcol[ca] = iA; invdcol[cb] = iB;
            }
        }
        __syncthreads();

        // ---- cross phase: 15 tournament rounds over 16 groups ----
        for (int r = 0; r < 15; ++r) {
            int GI, GJ;
            if (wv == 0) { GI = 15; GJ = r; }
            else { GI = (r + wv) % 15; GJ = (r - wv + 15) % 15; }
            const int pc = GI*8 + slot, qc0 = GJ*8 + slot;
            double2* Pp = (double2*)&Ad[pc*NSTR + 2*sub];
            double2* Pq = (double2*)&Ad[qc0*NSTR + 2*sub];
            double2 p8[8], q8[8];
            #pragma unroll
            for (int m = 0; m < 8; ++m) { p8[m] = Pp[m*8]; q8[m] = Pq[m*8]; }
            double np = colnorm[pc], nq = colnorm[qc0];
            double dp = dcol[pc], ip = invdcol[pc];
            double dq = dcol[qc0], iq = invdcol[qc0];
            bool wrote = false;
            #pragma unroll
            for (int s = 0; s < 8; ++s) {
                double g0 = 0.0, g1 = 0.0;
                #pragma unroll
                for (int m = 0; m < 4; ++m) {
                    g0 = fma(p8[m].x, q8[m].x, g0);
                    g0 = fma(p8[m].y, q8[m].y, g0);
                }
                #pragma unroll
                for (int m = 4; m < 8; ++m) {
                    g1 = fma(p8[m].x, q8[m].x, g1);
                    g1 = fma(p8[m].y, q8[m].y, g1);
                }
                double ga = slot8_sum(g0 + g1) * (dp*dq);   // TRUE gamma
                double g2 = ga*ga, pr = np*nq;
                const bool rot = (g2 > pr*1e-20);
                big |= rot;
                if (__any(rot)) {
                    double tt, cc, se, rc; ROT_FG(nq - np, ga, tt, cc, se, rc);
                    tt = rot ? tt : 0.0; cc = rot ? cc : 1.0;
                    se = rot ? se : 0.0; rc = rot ? rc : 1.0;
                    double arp = tt * dq * ip;
                    double brq = tt * dp * iq;
                    #pragma unroll
                    for (int m = 0; m < 8; ++m) {
                        double ox = p8[m].x, oy = p8[m].y;
                        p8[m].x = fma(-arp, q8[m].x, ox);
                        p8[m].y = fma(-arp, q8[m].y, oy);
                        q8[m].x = fma( brq, ox, q8[m].x);
                        q8[m].y = fma( brq, oy, q8[m].y);
                    }
                    double cs2 = 2.0*cc*se*ga;
                    double npn = fma(cc*cc, np, fma(se*se, nq, -cs2));
                    nq         = fma(se*se, np, fma(cc*cc, nq,  cs2));
                    np = npn;
                    dp *= cc; ip *= rc; dq *= cc; iq *= rc;
                    wrote = true;
                }
                if (s < 7) {
                    const int d8 = ((s ^ (s+1)) << 3);   // 8,24,8,56,8,24,8
                    if (d8 == 8) {
                        #pragma unroll
                        for (int m = 0; m < 8; ++m) {
                            q8[m].x = dpp_d<0x128>(q8[m].x);   // row_ror:8 == lane^8
                            q8[m].y = dpp_d<0x128>(q8[m].y);
                        }
                        nq = dpp_d<0x128>(nq); dq = dpp_d<0x128>(dq); iq = dpp_d<0x128>(iq);
                    } else {
                        #pragma unroll
                        for (int m = 0; m < 8; ++m) {
                            q8[m].x = __shfl_xor(q8[m].x, d8);
                            q8[m].y = __shfl_xor(q8[m].y, d8);
                        }
                        nq = __shfl_xor(nq, d8); dq = __shfl_xor(dq, d8); iq = __shfl_xor(iq, d8);
                    }
                }
            }
            if (wrote) {   // wave-uniform: set only under __any() branches
                #pragma unroll
                for (int m = 0; m < 8; ++m) Pp[m*8] = p8[m];
                const int qcf = GJ*8 + (slot ^ 7);
                double2* Pqw = (double2*)&Ad[qcf*NSTR + 2*sub];
                #pragma unroll
                for (int m = 0; m < 8; ++m) Pqw[m*8] = q8[m];
                if (sub == 0) {
                    colnorm[pc] = np; colnorm[qcf] = nq;
                    dcol[pc] = dp; dcol[qcf] = dq;
                    invdcol[pc] = ip; invdcol[qcf] = iq;
                }
            }
            __syncthreads();
        }

        // ---- convergence check ----
        unsigned long long bb = __ballot(big);
        if (lk == 0) redflag[wv] = (bb != 0ULL) ? 1 : 0;
        __syncthreads();
        if (t == 0) {
            int any = 0;
            for (int i = 0; i < 8; ++i) any |= redflag[i];
            convflag = !any;
        }
        __syncthreads();
        if (convflag) break;
    }
    __syncthreads();

    // ---- final scale fold: A = b*d ----
    for (int idx = t; idx < 16384; idx += 512) {
        int r = idx >> 7, c = idx & 127;
        Ad[c*NSTR + r] *= dcol[c];
    }
    __syncthreads();

    // ---- column norms (exact recompute), sort descending ----
    if (t < 128) {
        double s = 0.0;
        for (int r = 0; r < 128; ++r) { double v = Ad[t*NSTR + r]; s = fma(v, v, s); }
        sig_d[t] = sqrt(s);
    }
    __syncthreads();
    if (t < 128) {
        double my = sig_d[t]; int rk = 0;
        for (int c = 0; c < 128; ++c) {
            double v = sig_d[c];
            rk += (v > my) || (v == my && c < t);
        }
        perm[rk] = t;
    }
    __syncthreads();
    if (t < 64) { sigs_d[t] = sig_d[perm[t]]; sigf[t] = (float)sig_d[perm[t]]; }
    __syncthreads();

    // ---- compact U64 = A[:,perm[k]]/sigma into cols 0..63 (register-staged) ----
    {
        double tmp[16];
        #pragma unroll
        for (int i = 0; i < 16; ++i) {
            int idx = t + i*512; int k = idx >> 7, r = idx & 127;
            tmp[i] = Ad[perm[k]*NSTR + r] / sigs_d[k];
        }
        __syncthreads();
        #pragma unroll
        for (int i = 0; i < 16; ++i) {
            int idx = t + i*512; int k = idx >> 7, r = idx & 127;
            Ad[k*NSTR + r] = tmp[i];
        }
    }
    __syncthreads();

    // ---- V64 = M^T * U64 * Sigma^{-1} into cols 64..127 ----
    {
        const int j = t & 127, kh = (t >> 7)*16;
        double acc[16];
        #pragma unroll
        for (int m = 0; m < 16; ++m) acc[m] = 0.0;
        for (int r = 0; r < 128; ++r) {
            double mv = Mg[r*128 + j];
            #pragma unroll
            for (int m = 0; m < 16; ++m) acc[m] = fma(mv, Ad[(kh+m)*NSTR + r], acc[m]);
        }
        #pragma unroll
        for (int m = 0; m < 16; ++m) Ad[(64+kh+m)*NSTR + j] = acc[m] / sigs_d[kh+m];
    }
    __syncthreads();

    // ---- Householder QR (LAPACK signs) + org2r, U and V QRs CONCURRENT ----
    {
        const int h  = t >> 8;         // 0 = U, 1 = V
        const int t5 = t & 255;
        const int CB = h * 64;
        const int g4 = t5 >> 2, s4 = t5 & 3;
        // geqrf
        for (int j = 0; j < 64; ++j) {
            if (t5 < 64) {
                double ps = 0.0;
                for (int r = j + t5; r < 128; r += 64) { double v = Ad[(CB+j)*NSTR + r]; ps = fma(v, v, ps); }
                ps += dpp_d<0xB1>(ps);
                ps += dpp_d<0x4E>(ps);
                ps += dpp_d<0x141>(ps);
                ps += dpp_d<0x128>(ps);
                ps += __shfl_xor(ps, 16);
                ps += __shfl_xor(ps, 32);
                if (t5 == 0) {
                    double piv = Ad[(CB+j)*NSTR + j];
                    double nx = sqrt(ps);
                    double vj = piv + ((piv >= 0.0) ? nx : -nx);
                    double vn2 = ps - piv*piv + vj*vj;
                    tau2[h][j] = 2.0 / vn2;
                    vjs2[h][j] = vj;
                    Ad[(CB+j)*NSTR + j] = vj;
                }
            }
            __syncthreads();
            {
                int c = j + 1 + g4;
                if (c < 64) {
                    double w = 0.0;
                    for (int r = j + s4; r < 128; r += 4)
                        w = fma(Ad[(CB+j)*NSTR + r], Ad[(CB+c)*NSTR + r], w);
                    w += dpp_d<0xB1>(w);
                    w += dpp_d<0x4E>(w);
                    w *= tau2[h][j];
                    for (int r = j + s4; r < 128; r += 4)
                        Ad[(CB+c)*NSTR + r] -= w * Ad[(CB+j)*NSTR + r];
                }
            }
            __syncthreads();
        }
        // org2r (backward accumulation): Q = H_0 ... H_63 * E
        for (int j = 63; j >= 0; --j) {
            {
                int c = j + 1 + g4;
                if (c < 64) {
                    double w = 0.0;
                    for (int r = j + s4; r < 128; r += 4)
                        w = fma(Ad[(CB+j)*NSTR + r], Ad[(CB+c)*NSTR + r], w);
                    w += dpp_d<0xB1>(w);
                    w += dpp_d<0x4E>(w);
                    w *= tau2[h][j];
                    for (int r = j + s4; r < 128; r += 4)
                        Ad[(CB+c)*NSTR + r] -= w * Ad[(CB+j)*NSTR + r];
                }
            }
            __syncthreads();
            if (t5 < 128) {
                double qv;
                if (t5 < j) qv = 0.0;
                else {
                    double vt = Ad[(CB+j)*NSTR + t5];
                    qv = ((t5 == j) ? 1.0 : 0.0) - tau2[h][j]*vjs2[h][j]*vt;
                }
                Ad[(CB+j)*NSTR + t5] = qv;
            }
            __syncthreads();
        }
    }

    // ---- downcast U_st, Vq to fp32 (register-staged, regions overlap) ----
    {
        float tmpf[16];
        #pragma unroll
        for (int i = 0; i < 16; ++i) {
            int idx = t + i*512; int k = idx >> 7, r = idx & 127;
            tmpf[i] = (float)Ad[k*NSTR + r];
        }
        __syncthreads();
        #pragma unroll
        for (int i = 0; i < 16; ++i) {
            int idx = t + i*512; int k = idx >> 7, r = idx & 127;
            Af[U32_OFF + k*132 + r] = tmpf[i];
        }
        __syncthreads();
        #pragma unroll
        for (int i = 0; i < 16; ++i) {
            int idx = t + i*512; int k = idx >> 7, r = idx & 127;
            tmpf[i] = (float)Ad[(64+k)*NSTR + r];
        }
        __syncthreads();
        #pragma unroll
        for (int i = 0; i < 16; ++i) {
            int idx = t + i*512; int k = idx >> 7, r = idx & 127;
            Af[V32_OFF + k*132 + r] = tmpf[i];
        }
    }
    __syncthreads();

    // ---- MLP chain (fp32): relu chains; layer 3 also scales by sigma ----
    int SRCO = U32_OFF, DSTO = RA_OFF;
    const int n = t & 63, ib = (t >> 6)*16;
    for (int layer = 0; layer < 7; ++layer) {
        const float* wptr = (layer < 4) ? (w1g + layer*4096) : (w2g + (layer-3)*4096);
        for (int idx = t; idx < 4096; idx += 512) Af[WF_OFF + idx] = wptr[idx];
        __syncthreads();
        float acc[16];
        #pragma unroll
        for (int m = 0; m < 16; ++m) acc[m] = 0.f;
        for (int kk = 0; kk < 64; ++kk) {
            float wv2 = Af[WF_OFF + kk*64 + n];
            const float4* s4v = (const float4*)&Af[SRCO + kk*132 + ib];
            #pragma unroll
            for (int q4 = 0; q4 < 4; ++q4) {
                float4 v4 = s4v[q4];
                acc[q4*4+0] = fmaf(v4.x, wv2, acc[q4*4+0]);
                acc[q4*4+1] = fmaf(v4.y, wv2, acc[q4*4+1]);
                acc[q4*4+2] = fmaf(v4.z, wv2, acc[q4*4+2]);
                acc[q4*4+3] = fmaf(v4.w, wv2, acc[q4*4+3]);
            }
        }
        float sc = (layer == 3) ? sigf[n] : 1.f;
        #pragma unroll
        for (int q4 = 0; q4 < 4; ++q4) {
            float4 o;
            o.x = fmaxf(acc[q4*4+0], 0.f)*sc;
            o.y = fmaxf(acc[q4*4+1], 0.f)*sc;
            o.z = fmaxf(acc[q4*4+2], 0.f)*sc;
            o.w = fmaxf(acc[q4*4+3], 0.f)*sc;
            ((float4*)&Af[DSTO + n*132 + ib])[q4] = o;
        }
        __syncthreads();
        SRCO = DSTO; DSTO = (DSTO == RA_OFF) ? RB_OFF : RA_OFF;
    }

    // ---- T = r @ Vh_st, write fp32 into this block's own M slot ----
    {
        float* Tb = (float*)((char*)wsM + (size_t)b*131072);
        const int j2 = t & 127, ih = (t >> 7)*32;
        float acc2[32];
        #pragma unroll
        for (int m = 0; m < 32; ++m) acc2[m] = 0.f;
        for (int kk = 0; kk < 64; ++kk) {
            float vv = Af[V32_OFF + kk*132 + j2];
            const float4* r4 = (const float4*)&Af[RA_OFF + kk*132 + ih];
            #pragma unroll
            for (int q4 = 0; q4 < 8; ++q4) {
                float4 v4 = r4[q4];
                acc2[q4*4+0] = fmaf(v4.x, vv, acc2[q4*4+0]);
                acc2[q4*4+1] = fmaf(v4.y, vv, acc2[q4*4+1]);
                acc2[q4*4+2] = fmaf(v4.z, vv, acc2[q4*4+2]);
                acc2[q4*4+3] = fmaf(v4.w, vv, acc2[q4*4+3]);
            }
        }
        #pragma unroll
        for (int m = 0; m < 32; ++m) Tb[(size_t)(ih+m)*128 + j2] = acc2[m];
    }
}

// ---------------- Stage 3: out = weightsO @ vec(T) per batch (K-split) ----------------
__global__ __launch_bounds__(256) void k_out(const char* __restrict__ wsbase,
        const float* __restrict__ wO, float* __restrict__ part)
{
    __shared__ float Wt[128*65];
    __shared__ float Tt[8*64];
    const int t = threadIdx.x;
    const int bt = blockIdx.x & 31, ks = blockIdx.x >> 5;
    const int a = t & 127, bh = (t >> 7)*4;
    float acc[4] = {0.f, 0.f, 0.f, 0.f};
    for (int cc = 0; cc < 32; ++cc) {
        const int kbase = ks*2048 + cc*64;
        __syncthreads();
        for (int idx = t; idx < 8192; idx += 256) {
            int aa = idx >> 6, nn = idx & 63;
            Wt[aa*65 + nn] = wO[aa*16384 + kbase + nn];
        }
        for (int idx = t; idx < 512; idx += 256) {
            int bl = idx >> 6, nn = idx & 63;
            const float* Tb = (const float*)(wsbase + (size_t)(bt*8 + bl)*131072);
            Tt[bl*64 + nn] = Tb[kbase + nn];
        }
        __syncthreads();
        for (int nn = 0; nn < 64; ++nn) {
            float wv = Wt[a*65 + nn];
            #pragma unroll
            for (int m = 0; m < 4; ++m) acc[m] = fmaf(Tt[(bh+m)*64 + nn], wv, acc[m]);
        }
    }
    #pragma unroll
    for (int m = 0; m < 4; ++m)
        part[ks*32768 + (bt*8 + bh + m)*128 + a] = acc[m];
}

__global__ __launch_bounds__(256) void k_red(const float* __restrict__ part,
                                             float* __restrict__ out)
{
    int i = blockIdx.x*256 + threadIdx.x;
    float s = 0.f;
    #pragma unroll
    for (int ks = 0; ks < 8; ++ks) s += part[ks*32768 + i];
    out[i] = s;
}

extern "C" void kernel_launch(void* const* d_in, const int* in_sizes, int n_in,
                              void* d_out, int out_size, void* d_ws, size_t ws_size,
                              hipStream_t stream)
{
    (void)in_sizes; (void)n_in; (void)out_size; (void)ws_size;
    const float* obs = (const float*)d_in[0];
    const float* w1  = (const float*)d_in[1];
    const float* w2  = (const float*)d_in[2];
    const float* wO  = (const float*)d_in[3];
    const float* c1w = (const float*)d_in[4];
    const float* c1b = (const float*)d_in[5];
    const float* c2w = (const float*)d_in[6];
    const float* c2b = (const float*)d_in[7];
    double* M = (double*)d_ws;
    float* part = (float*)((char*)d_ws + 33554432);

    k_feat<<<dim3(16384), dim3(256), 0, stream>>>(obs, c1w, c1b, c2w, c2b, M);
    k_svd <<<dim3(256),   dim3(512), 0, stream>>>(w1, w2, M);
    k_out <<<dim3(256),   dim3(256), 0, stream>>>((const char*)d_ws, wO, part);
    k_red <<<dim3(128),   dim3(256), 0, stream>>>(part, (float*)d_out);
}

// Round 14
// 1874.302 us; speedup vs baseline: 1.0439x; 1.0439x over previous
//
#include <hip/hip_runtime.h>

// ws layout (bytes):
//   [0, 33554432)            M as double, 256 blocks x 16384 (131072 B each).
//                            After k_svd, first 65536 B of each block's slot is
//                            overwritten with T as float (16384 floats).
//   [33554432, 34603008)     GEMM partials: 8 * 256 * 128 floats

#define NSTR 132               // double stride for 128-row columns in LDS (EVEN: 16B-aligned double2)
// float-phase offsets (in floats) inside the shared pool
#define U32_OFF 0
#define V32_OFF 8448
#define RA_OFF  16896
#define RB_OFF  25344
#define WF_OFF  33792
#define POOL_BYTES 151552      // 37888 floats; double phase needs 128*132*8 = 135168 B

// zero-cost fence (validated R2/R3): orders DS ops across sub-rounds within a
// wave; HW DS pipe is in-order per wave, so a compile-time fence suffices.
#define WAVE_FENCE() do { __asm__ __volatile__("" ::: "memory"); \
                          __builtin_amdgcn_wave_barrier();        \
                          __asm__ __volatile__("" ::: "memory"); } while (0)

// DPP lane-permute on a double (2x update_dpp on the 32-bit halves). VALU-pipe
// (~2cy/op) vs ds_bpermute (~40cy LDS-pipe) — used for intra-8-lane reduces.
template<int CTRL>
__device__ __forceinline__ double dpp_d(double x) {
    union { double d; int i[2]; } u, r;
    u.d = x;
    r.i[0] = __builtin_amdgcn_update_dpp(0, u.i[0], CTRL, 0xF, 0xF, true);
    r.i[1] = __builtin_amdgcn_update_dpp(0, u.i[1], CTRL, 0xF, 0xF, true);
    return r.d;
}
// lane^MASK (MASK<32) on a double via single ds_swizzle per 32-bit half
// (BitMode offset = (xor<<10)|0x1F — guide-documented). Cheaper than
// ds_bpermute: no per-lane address setup.
template<int MASK>
__device__ __forceinline__ double swz_d(double x) {
    union { double d; int i[2]; } u, r;
    u.d = x;
    r.i[0] = __builtin_amdgcn_ds_swizzle(u.i[0], (MASK<<10)|0x1F);
    r.i[1] = __builtin_amdgcn_ds_swizzle(u.i[1], (MASK<<10)|0x1F);
    return r.d;
}
// sum over the 8 lanes of a slot (lanes 8-aligned): xor1 (quad_perm [1,0,3,2]),
// xor2 (quad_perm [2,3,0,1]), cross-quad (row_half_mirror). All-VALU.
// Validated R7/R10: leaves the identical slot-sum in ALL 8 lanes.
__device__ __forceinline__ double slot8_sum(double g) {
    g += dpp_d<0xB1>(g);
    g += dpp_d<0x4E>(g);
    g += dpp_d<0x141>(g);
    return g;
}

// Fast Jacobi rotation angle (R5-validated form, RESTORED): fp32 chain + one
// fp64 Newton renorm so c^2+s^2 = 1 + O(1e-14). R13 ERRATum: dropping the
// Newton renorm makes the accumulated rotation product non-orthogonal at the
// ~1e-5 level (random-walk of rsqrtf's 2e-7 error over ~1300 rotations,
// applied in intermediate frames — NOT a clean column scaling). Singular
// vectors near degeneracies (gap ~1e-4) then err by ~||E||/gap ~ 0.1 rad
// -> absmax 3.2e-2. The renorm keeps ||E|| ~ 4e-13. It stays.
#define ROT_ANGLE(d_, g_, cc_, ss_) do {                                  \
    float d32 = (float)(d_), g32 = (float)(g_);                           \
    float h32 = sqrtf(fmaf(d32, d32, 4.0f*g32*g32));                      \
    float den = d32 + copysignf(h32, d32);                                \
    float t32 = __fdividef(2.0f*g32, den);                                \
    float c32 = rsqrtf(fmaf(t32, t32, 1.0f));                             \
    cc_ = (double)c32; ss_ = (double)(t32*c32);                           \
    double corr_ = 0.5*(3.0 - fma(cc_,cc_, ss_*ss_));                     \
    cc_ *= corr_; ss_ *= corr_;                                           \
} while (0)

// ---------------- Stage 1: features + conv chain -> M (fp64) ----------------
__global__ __launch_bounds__(256) void k_feat(const float* __restrict__ obs,
        const float* __restrict__ c1w, const float* __restrict__ c1b,
        const float* __restrict__ c2w, const float* __restrict__ c2b,
        double* __restrict__ M)
{
    __shared__ __align__(16) float lds[256*29];
    const int t = threadIdx.x;
    const float4* obs4 = (const float4*)obs;
    float4* lds4 = (float4*)lds;
    const size_t base4 = (size_t)blockIdx.x * 1856;
    for (int idx = t; idx < 1856; idx += 256) lds4[idx] = obs4[base4 + idx];
    __syncthreads();
    const float* o = &lds[t*29];
    double f0=0,f1=0,f2=0,f3=0,f4=0,f5=0;
    #pragma unroll
    for (int d=1; d<5; ++d) f0 += (double)o[d]*d;
    #pragma unroll
    for (int d=1; d<5; ++d) f1 += (double)o[5+d]*d;
    f2 = (double)o[11] + 2.0*(double)o[12];
    #pragma unroll
    for (int d=1; d<8; ++d) f3 += (double)o[13+d]*d;
    #pragma unroll
    for (int d=1; d<6; ++d) f4 += (double)o[21+d]*d;
    f5 = (double)o[28];
    const double w0=c1w[0], w1=c1w[1], w2=c1w[2], w3=c1w[3], b1=c1b[0];
    const double cw0=c2w[0], cw1=c2w[1], b2=c2b[0];
    // conv1 stride2 pad2 k4: 6 -> 4 -> 3 -> 2 ; conv2 k2: -> 1
    double y0 = b1 + f0*w2 + f1*w3;
    double y1 = b1 + f0*w0 + f1*w1 + f2*w2 + f3*w3;
    double y2 = b1 + f2*w0 + f3*w1 + f4*w2 + f5*w3;
    double y3 = b1 + f4*w0 + f5*w1;
    double z0 = b1 + y0*w2 + y1*w3;
    double z1 = b1 + y0*w0 + y1*w1 + y2*w2 + y3*w3;
    double z2 = b1 + y2*w0 + y3*w1;
    double u0 = b1 + z0*w2 + z1*w3;
    double u1 = b1 + z0*w0 + z1*w1 + z2*w2;
    double m  = b2 + u0*cw0 + u1*cw1;
    M[(size_t)blockIdx.x*256 + t] = m;
}

// ---------------- Stage 2: per-batch SVD + QR signs + MLP + T ----------------
__global__ __launch_bounds__(512, 2) void k_svd(
        const float* __restrict__ w1g, const float* __restrict__ w2g,
        double* __restrict__ wsM)
{
    __shared__ __align__(16) char smem[POOL_BYTES];
    double* Ad = (double*)smem;
    float*  Af = (float*)smem;
    __shared__ double colnorm[128];
    __shared__ double sig_d[128];
    __shared__ double sigs_d[64];
    __shared__ float  sigf[64];
    __shared__ double tau2[2][64];
    __shared__ double vjs2[2][64];
    __shared__ int    perm[128];
    __shared__ int    redflag[8];
    __shared__ int    convflag;

    const int t = threadIdx.x;
    const int b = blockIdx.x;
    double* Mg = wsM + (size_t)b*16384;

    const int wv   = t >> 6;       // wave 0..7
    const int lk   = t & 63;       // lane in wave
    const int slot = lk >> 3;      // pair slot 0..7
    const int sub  = lk & 7;       // lane in slot

    // load M column-major into LDS (fp64)
    for (int idx = t; idx < 16384; idx += 512) {
        int r = idx >> 7, c = idx & 127;
        Ad[c*NSTR + r] = Mg[idx];
    }
    __syncthreads();

    // ---- initial column norms (maintained analytically through rotations) ----
    {
        const int gs = t >> 3;     // global slot 0..63
        #pragma unroll
        for (int h = 0; h < 2; ++h) {
            const int c = gs + 64*h;
            const double2* P = (const double2*)&Ad[c*NSTR + 2*sub];
            double sacc = 0.0;
            #pragma unroll
            for (int m = 0; m < 8; ++m) {
                double2 v = P[m*8];
                sacc = fma(v.x, v.x, sacc); sacc = fma(v.y, v.y, sacc);
            }
            sacc = slot8_sum(sacc);
            if (sub == 0) colnorm[c] = sacc;
        }
    }
    __syncthreads();

    // ---- de Rijk pre-sort: permute columns by descending norm (full 128
    // columns: i<32, 16384 elems — the R8/R9 bug was i<16) ----
    if (t < 128) {
        double my = colnorm[t]; int rk = 0;
        for (int c2 = 0; c2 < 128; ++c2) {
            double v = colnorm[c2];
            rk += (v > my) || (v == my && c2 < t);
        }
        perm[rk] = t;
    }
    __syncthreads();
    {
        double tmp[32]; double cn = 0.0;
        #pragma unroll
        for (int i = 0; i < 32; ++i) {
            int idx = t + i*512; int k = idx >> 7, r = idx & 127;
            tmp[i] = Ad[perm[k]*NSTR + r];
        }
        if (t < 128) cn = colnorm[perm[t]];
        __syncthreads();
        #pragma unroll
        for (int i = 0; i < 32; ++i) {
            int idx = t + i*512; int k = idx >> 7, r = idx & 127;
            Ad[k*NSTR + r] = tmp[i];
        }
        if (t < 128) colnorm[t] = cn;
    }
    __syncthreads();

    // ---- hierarchical one-sided Jacobi, fp64, THRESHOLD-JACOBI gating ----
    // Gray-code q-visit order: c_seq = {0,1,3,2,6,7,5,4} makes the migration
    // deltas {8,16,8,32,8,16,8} lanes — ^8 via DPP ror8 (VALU), ^16 via single
    // ds_swizzle, only one ^32 via shfl. Final q position is slot^4.
    for (int sweep = 0; sweep < 16; ++sweep) {
        int big = 0;

        // ---- internal phase: wave wv owns cols 16wv..16wv+15 ----
        {
            const int ca = 16*wv + slot, cb = ca + 8;
            double2* PA = (double2*)&Ad[ca*NSTR + 2*sub];
            double2* PB = (double2*)&Ad[cb*NSTR + 2*sub];
            double2 a8[8], b8[8];
            #pragma unroll
            for (int m = 0; m < 8; ++m) { a8[m] = PA[m*8]; b8[m] = PB[m*8]; }
            double nA = colnorm[ca], nB = colnorm[cb];
            for (int s = 1; s < 8; ++s) {
                const int pa = 16*wv + (slot ^ s), pb = pa + 8;
                const int d8 = s << 3;
                const double2* QA = (const double2*)&Ad[pa*NSTR + 2*sub];
                const double2* QB = (const double2*)&Ad[pb*NSTR + 2*sub];
                double2 ya[8], yb[8];
                #pragma unroll
                for (int m = 0; m < 8; ++m) { ya[m] = QA[m*8]; yb[m] = QB[m*8]; }
                double nya, nyb;
                if (s == 1) {
                    nya = dpp_d<0x128>(nA);
                    nyb = dpp_d<0x128>(nB);
                } else {
                    nya = __shfl_xor(nA, d8);
                    nyb = __shfl_xor(nB, d8);
                }
                double gA0=0.0, gA1=0.0, gA2=0.0, gA3=0.0;
                double gB0=0.0, gB1=0.0, gB2=0.0, gB3=0.0;
                #pragma unroll
                for (int m = 0; m < 2; ++m) {
                    gA0 = fma(a8[m].x, ya[m].x, gA0); gA0 = fma(a8[m].y, ya[m].y, gA0);
                    gB0 = fma(b8[m].x, yb[m].x, gB0); gB0 = fma(b8[m].y, yb[m].y, gB0);
                }
                #pragma unroll
                for (int m = 2; m < 4; ++m) {
                    gA1 = fma(a8[m].x, ya[m].x, gA1); gA1 = fma(a8[m].y, ya[m].y, gA1);
                    gB1 = fma(b8[m].x, yb[m].x, gB1); gB1 = fma(b8[m].y, yb[m].y, gB1);
                }
                #pragma unroll
                for (int m = 4; m < 6; ++m) {
                    gA2 = fma(a8[m].x, ya[m].x, gA2); gA2 = fma(a8[m].y, ya[m].y, gA2);
                    gB2 = fma(b8[m].x, yb[m].x, gB2); gB2 = fma(b8[m].y, yb[m].y, gB2);
                }
                #pragma unroll
                for (int m = 6; m < 8; ++m) {
                    gA3 = fma(a8[m].x, ya[m].x, gA3); gA3 = fma(a8[m].y, ya[m].y, gA3);
                    gB3 = fma(b8[m].x, yb[m].x, gB3); gB3 = fma(b8[m].y, yb[m].y, gB3);
                }
                double gA = slot8_sum((gA0 + gA1) + (gA2 + gA3));
                double gB = slot8_sum((gB0 + gB1) + (gB2 + gB3));
                const int pside = (slot < (slot ^ s));
                // --- A rotation (wave-vote skip; per-lane mask inside) ---
                {
                    double al = pside ? nA : nya, be = pside ? nya : nA;
                    double g2 = gA*gA, pr = al*be;
                    const bool rot = (g2 > pr*1e-20);
                    big |= rot;
                    if (__any(rot)) {
                        double cc, ss; ROT_ANGLE(be - al, gA, cc, ss);
                        cc = rot ? cc : 1.0; ss = rot ? ss : 0.0;
                        double sgn = pside ? -ss : ss;
                        #pragma unroll
                        for (int m = 0; m < 8; ++m) {
                            a8[m].x = fma(sgn, ya[m].x, cc*a8[m].x);
                            a8[m].y = fma(sgn, ya[m].y, cc*a8[m].y);
                        }
                        double cs2 = 2.0*cc*ss*gA;
                        nA = pside ? fma(cc*cc, nA, fma(ss*ss, nya, -cs2))
                                   : fma(ss*ss, nya, fma(cc*cc, nA,  cs2));
                        #pragma unroll
                        for (int m = 0; m < 8; ++m) PA[m*8] = a8[m];
                    }
                }
                // --- B rotation ---
                {
                    double al = pside ? nB : nyb, be = pside ? nyb : nB;
                    double g2 = gB*gB, pr = al*be;
                    const bool rot = (g2 > pr*1e-20);
                    big |= rot;
                    if (__any(rot)) {
                        double cc, ss; ROT_ANGLE(be - al, gB, cc, ss);
                        cc = rot ? cc : 1.0; ss = rot ? ss : 0.0;
                        double sgn = pside ? -ss : ss;
                        #pragma unroll
                        for (int m = 0; m < 8; ++m) {
                            b8[m].x = fma(sgn, yb[m].x, cc*b8[m].x);
                            b8[m].y = fma(sgn, yb[m].y, cc*b8[m].y);
                        }
                        double cs2 = 2.0*cc*ss*gB;
                        nB = pside ? fma(cc*cc, nB, fma(ss*ss, nyb, -cs2))
                                   : fma(ss*ss, nyb, fma(cc*cc, nB,  cs2));
                        #pragma unroll
                        for (int m = 0; m < 8; ++m) PB[m*8] = b8[m];
                    }
                }
                WAVE_FENCE();
            }
            if (sub == 0) { colnorm[ca] = nA; colnorm[cb] = nB; }
        }
        __syncthreads();

        // ---- cross phase: 15 tournament rounds over 16 groups ----
        for (int r = 0; r < 15; ++r) {
            int GI, GJ;
            if (wv == 0) { GI = 15; GJ = r; }
            else { GI = (r + wv) % 15; GJ = (r - wv + 15) % 15; }
            const int pc = GI*8 + slot, qc0 = GJ*8 + slot;   // c_seq[0] = 0
            double2* Pp = (double2*)&Ad[pc*NSTR + 2*sub];
            double2* Pq = (double2*)&Ad[qc0*NSTR + 2*sub];
            double2 p8[8], q8[8];
            #pragma unroll
            for (int m = 0; m < 8; ++m) { p8[m] = Pp[m*8]; q8[m] = Pq[m*8]; }
            double np = colnorm[pc], nq = colnorm[qc0];
            bool wrote = false;
            // Gray-code visit order: deltas 8,16,8,32,8,16,8 (lanes)
            constexpr int CSEQ[8] = {0,1,3,2,6,7,5,4};
            #pragma unroll
            for (int s = 0; s < 8; ++s) {
                double g0=0.0, g1=0.0, g2a=0.0, g3=0.0;
                #pragma unroll
                for (int m = 0; m < 2; ++m) {
                    g0 = fma(p8[m].x, q8[m].x, g0);
                    g0 = fma(p8[m].y, q8[m].y, g0);
                }
                #pragma unroll
                for (int m = 2; m < 4; ++m) {
                    g1 = fma(p8[m].x, q8[m].x, g1);
                    g1 = fma(p8[m].y, q8[m].y, g1);
                }
                #pragma unroll
                for (int m = 4; m < 6; ++m) {
                    g2a = fma(p8[m].x, q8[m].x, g2a);
                    g2a = fma(p8[m].y, q8[m].y, g2a);
                }
                #pragma unroll
                for (int m = 6; m < 8; ++m) {
                    g3 = fma(p8[m].x, q8[m].x, g3);
                    g3 = fma(p8[m].y, q8[m].y, g3);
                }
                double ga = slot8_sum((g0 + g1) + (g2a + g3));
                double g2 = ga*ga, pr = np*nq;
                const bool rot = (g2 > pr*1e-20);
                big |= rot;
                if (__any(rot)) {
                    double cc, ss; ROT_ANGLE(nq - np, ga, cc, ss);
                    cc = rot ? cc : 1.0; ss = rot ? ss : 0.0;
                    #pragma unroll
                    for (int m = 0; m < 8; ++m) {
                        double ox = p8[m].x, oy = p8[m].y;
                        p8[m].x = fma(-ss, q8[m].x, cc*ox);
                        p8[m].y = fma(-ss, q8[m].y, cc*oy);
                        q8[m].x = fma( ss, ox, cc*q8[m].x);
                        q8[m].y = fma( ss, oy, cc*q8[m].y);
                    }
                    double cs2 = 2.0*cc*ss*ga;
                    double npn = fma(cc*cc, np, fma(ss*ss, nq, -cs2));
                    nq         = fma(ss*ss, np, fma(cc*cc, nq,  cs2));
                    np = npn;
                    wrote = true;
                }
                if (s < 7) {
                    const int d8 = ((CSEQ[s] ^ CSEQ[s+1]) << 3);   // 8,16,8,32,8,16,8
                    if (d8 == 8) {
                        #pragma unroll
                        for (int m = 0; m < 8; ++m) {
                            q8[m].x = dpp_d<0x128>(q8[m].x);   // row_ror:8 == lane^8
                            q8[m].y = dpp_d<0x128>(q8[m].y);
                        }
                        nq = dpp_d<0x128>(nq);
                    } else if (d8 == 16) {
                        #pragma unroll
                        for (int m = 0; m < 8; ++m) {
                            q8[m].x = swz_d<16>(q8[m].x);      // lane^16, single swizzle
                            q8[m].y = swz_d<16>(q8[m].y);
                        }
                        nq = swz_d<16>(nq);
                    } else {
                        #pragma unroll
                        for (int m = 0; m < 8; ++m) {
                            q8[m].x = __shfl_xor(q8[m].x, 32);
                            q8[m].y = __shfl_xor(q8[m].y, 32);
                        }
                        nq = __shfl_xor(nq, 32);
                    }
                }
            }
            if (wrote) {   // wave-uniform: set only under __any() branches
                #pragma unroll
                for (int m = 0; m < 8; ++m) Pp[m*8] = p8[m];
                const int qcf = GJ*8 + (slot ^ 4);   // final position of CSEQ
                double2* Pqw = (double2*)&Ad[qcf*NSTR + 2*sub];
                #pragma unroll
                for (int m = 0; m < 8; ++m) Pqw[m*8] = q8[m];
                if (sub == 0) { colnorm[pc] = np; colnorm[qcf] = nq; }
            }
            __syncthreads();
        }

        // ---- convergence check ----
        unsigned long long bb = __ballot(big);
        if (lk == 0) redflag[wv] = (bb != 0ULL) ? 1 : 0;
        __syncthreads();
        if (t == 0) {
            int any = 0;
            for (int i = 0; i < 8; ++i) any |= redflag[i];
            convflag = !any;
        }
        __syncthreads();
        if (convflag) break;
    }
    __syncthreads();

    // ---- column norms (exact recompute), sort descending ----
    if (t < 128) {
        double s = 0.0;
        for (int r = 0; r < 128; ++r) { double v = Ad[t*NSTR + r]; s = fma(v, v, s); }
        sig_d[t] = sqrt(s);
    }
    __syncthreads();
    if (t < 128) {
        double my = sig_d[t]; int rk = 0;
        for (int c = 0; c < 128; ++c) {
            double v = sig_d[c];
            rk += (v > my) || (v == my && c < t);
        }
        perm[rk] = t;
    }
    __syncthreads();
    if (t < 64) { sigs_d[t] = sig_d[perm[t]]; sigf[t] = (float)sig_d[perm[t]]; }
    __syncthreads();

    // ---- compact U64 = A[:,perm[k]]/sigma into cols 0..63 (register-staged) ----
    {
        double tmp[16];
        #pragma unroll
        for (int i = 0; i < 16; ++i) {
            int idx = t + i*512; int k = idx >> 7, r = idx & 127;
            tmp[i] = Ad[perm[k]*NSTR + r] / sigs_d[k];
        }
        __syncthreads();
        #pragma unroll
        for (int i = 0; i < 16; ++i) {
            int idx = t + i*512; int k = idx >> 7, r = idx & 127;
            Ad[k*NSTR + r] = tmp[i];
        }
    }
    __syncthreads();

    // ---- V64 = M^T * U64 * Sigma^{-1} into cols 64..127 ----
    {
        const int j = t & 127, kh = (t >> 7)*16;
        double acc[16];
        #pragma unroll
        for (int m = 0; m < 16; ++m) acc[m] = 0.0;
        for (int r = 0; r < 128; ++r) {
            double mv = Mg[r*128 + j];
            #pragma unroll
            for (int m = 0; m < 16; ++m) acc[m] = fma(mv, Ad[(kh+m)*NSTR + r], acc[m]);
        }
        #pragma unroll
        for (int m = 0; m < 16; ++m) Ad[(64+kh+m)*NSTR + j] = acc[m] / sigs_d[kh+m];
    }
    __syncthreads();

    // ---- Householder QR (LAPACK signs) + org2r, U and V QRs CONCURRENT ----
    {
        const int h  = t >> 8;         // 0 = U, 1 = V
        const int t5 = t & 255;
        const int CB = h * 64;
        const int g4 = t5 >> 2, s4 = t5 & 3;
        // geqrf
        for (int j = 0; j < 64; ++j) {
            if (t5 < 64) {
                double ps = 0.0;
                for (int r = j + t5; r < 128; r += 64) { double v = Ad[(CB+j)*NSTR + r]; ps = fma(v, v, ps); }
                ps += dpp_d<0xB1>(ps);
                ps += dpp_d<0x4E>(ps);
                ps += dpp_d<0x141>(ps);
                ps += dpp_d<0x128>(ps);
                ps += __shfl_xor(ps, 16);
                ps += __shfl_xor(ps, 32);
                if (t5 == 0) {
                    double piv = Ad[(CB+j)*NSTR + j];
                    double nx = sqrt(ps);
                    double vj = piv + ((piv >= 0.0) ? nx : -nx);
                    double vn2 = ps - piv*piv + vj*vj;
                    tau2[h][j] = 2.0 / vn2;
                    vjs2[h][j] = vj;
                    Ad[(CB+j)*NSTR + j] = vj;
                }
            }
            __syncthreads();
            {
                int c = j + 1 + g4;
                if (c < 64) {
                    double w = 0.0;
                    for (int r = j + s4; r < 128; r += 4)
                        w = fma(Ad[(CB+j)*NSTR + r], Ad[(CB+c)*NSTR + r], w);
                    w += dpp_d<0xB1>(w);
                    w += dpp_d<0x4E>(w);
                    w *= tau2[h][j];
                    for (int r = j + s4; r < 128; r += 4)
                        Ad[(CB+c)*NSTR + r] -= w * Ad[(CB+j)*NSTR + r];
                }
            }
            __syncthreads();
        }
        // org2r (backward accumulation): Q = H_0 ... H_63 * E
        for (int j = 63; j >= 0; --j) {
            {
                int c = j + 1 + g4;
                if (c < 64) {
                    double w = 0.0;
                    for (int r = j + s4; r < 128; r += 4)
                        w = fma(Ad[(CB+j)*NSTR + r], Ad[(CB+c)*NSTR + r], w);
                    w += dpp_d<0xB1>(w);
                    w += dpp_d<0x4E>(w);
                    w *= tau2[h][j];
                    for (int r = j + s4; r < 128; r += 4)
                        Ad[(CB+c)*NSTR + r] -= w * Ad[(CB+j)*NSTR + r];
                }
            }
            __syncthreads();
            if (t5 < 128) {
                double qv;
                if (t5 < j) qv = 0.0;
                else {
                    double vt = Ad[(CB+j)*NSTR + t5];
                    qv = ((t5 == j) ? 1.0 : 0.0) - tau2[h][j]*vjs2[h][j]*vt;
                }
                Ad[(CB+j)*NSTR + t5] = qv;
            }
            __syncthreads();
        }
    }

    // ---- downcast U_st, Vq to fp32 (register-staged, regions overlap) ----
    {
        float tmpf[16];
        #pragma unroll
        for (int i = 0; i < 16; ++i) {
            int idx = t + i*512; int k = idx >> 7, r = idx & 127;
            tmpf[i] = (float)Ad[k*NSTR + r];
        }
        __syncthreads();
        #pragma unroll
        for (int i = 0; i < 16; ++i) {
            int idx = t + i*512; int k = idx >> 7, r = idx & 127;
            Af[U32_OFF + k*132 + r] = tmpf[i];
        }
        __syncthreads();
        #pragma unroll
        for (int i = 0; i < 16; ++i) {
            int idx = t + i*512; int k = idx >> 7, r = idx & 127;
            tmpf[i] = (float)Ad[(64+k)*NSTR + r];
        }
        __syncthreads();
        #pragma unroll
        for (int i = 0; i < 16; ++i) {
            int idx = t + i*512; int k = idx >> 7, r = idx & 127;
            Af[V32_OFF + k*132 + r] = tmpf[i];
        }
    }
    __syncthreads();

    // ---- MLP chain (fp32): relu chains; layer 3 also scales by sigma ----
    int SRCO = U32_OFF, DSTO = RA_OFF;
    const int n = t & 63, ib = (t >> 6)*16;
    for (int layer = 0; layer < 7; ++layer) {
        const float* wptr = (layer < 4) ? (w1g + layer*4096) : (w2g + (layer-3)*4096);
        for (int idx = t; idx < 4096; idx += 512) Af[WF_OFF + idx] = wptr[idx];
        __syncthreads();
        float acc[16];
        #pragma unroll
        for (int m = 0; m < 16; ++m) acc[m] = 0.f;
        for (int kk = 0; kk < 64; ++kk) {
            float wv2 = Af[WF_OFF + kk*64 + n];
            const float4* s4v = (const float4*)&Af[SRCO + kk*132 + ib];
            #pragma unroll
            for (int q4 = 0; q4 < 4; ++q4) {
                float4 v4 = s4v[q4];
                acc[q4*4+0] = fmaf(v4.x, wv2, acc[q4*4+0]);
                acc[q4*4+1] = fmaf(v4.y, wv2, acc[q4*4+1]);
                acc[q4*4+2] = fmaf(v4.z, wv2, acc[q4*4+2]);
                acc[q4*4+3] = fmaf(v4.w, wv2, acc[q4*4+3]);
            }
        }
        float sc = (layer == 3) ? sigf[n] : 1.f;
        #pragma unroll
        for (int q4 = 0; q4 < 4; ++q4) {
            float4 o;
            o.x = fmaxf(acc[q4*4+0], 0.f)*sc;
            o.y = fmaxf(acc[q4*4+1], 0.f)*sc;
            o.z = fmaxf(acc[q4*4+2], 0.f)*sc;
            o.w = fmaxf(acc[q4*4+3], 0.f)*sc;
            ((float4*)&Af[DSTO + n*132 + ib])[q4] = o;
        }
        __syncthreads();
        SRCO = DSTO; DSTO = (DSTO == RA_OFF) ? RB_OFF : RA_OFF;
    }

    // ---- T = r @ Vh_st, write fp32 into this block's own M slot ----
    {
        float* Tb = (float*)((char*)wsM + (size_t)b*131072);
        const int j2 = t & 127, ih = (t >> 7)*32;
        float acc2[32];
        #pragma unroll
        for (int m = 0; m < 32; ++m) acc2[m] = 0.f;
        for (int kk = 0; kk < 64; ++kk) {
            float vv = Af[V32_OFF + kk*132 + j2];
            const float4* r4 = (const float4*)&Af[RA_OFF + kk*132 + ih];
            #pragma unroll
            for (int q4 = 0; q4 < 8; ++q4) {
                float4 v4 = r4[q4];
                acc2[q4*4+0] = fmaf(v4.x, vv, acc2[q4*4+0]);
                acc2[q4*4+1] = fmaf(v4.y, vv, acc2[q4*4+1]);
                acc2[q4*4+2] = fmaf(v4.z, vv, acc2[q4*4+2]);
                acc2[q4*4+3] = fmaf(v4.w, vv, acc2[q4*4+3]);
            }
        }
        #pragma unroll
        for (int m = 0; m < 32; ++m) Tb[(size_t)(ih+m)*128 + j2] = acc2[m];
    }
}

// ---------------- Stage 3: out = weightsO @ vec(T) per batch (K-split) ----------------
__global__ __launch_bounds__(256) void k_out(const char* __restrict__ wsbase,
        const float* __restrict__ wO, float* __restrict__ part)
{
    __shared__ float Wt[128*65];
    __shared__ float Tt[8*64];
    const int t = threadIdx.x;
    const int bt = blockIdx.x & 31, ks = blockIdx.x >> 5;
    const int a = t & 127, bh = (t >> 7)*4;
    float acc[4] = {0.f, 0.f, 0.f, 0.f};
    for (int cc = 0; cc < 32; ++cc) {
        const int kbase = ks*2048 + cc*64;
        __syncthreads();
        for (int idx = t; idx < 8192; idx += 256) {
            int aa = idx >> 6, nn = idx & 63;
            Wt[aa*65 + nn] = wO[aa*16384 + kbase + nn];
        }
        for (int idx = t; idx < 512; idx += 256) {
            int bl = idx >> 6, nn = idx & 63;
            const float* Tb = (const float*)(wsbase + (size_t)(bt*8 + bl)*131072);
            Tt[bl*64 + nn] = Tb[kbase + nn];
        }
        __syncthreads();
        for (int nn = 0; nn < 64; ++nn) {
            float wv = Wt[a*65 + nn];
            #pragma unroll
            for (int m = 0; m < 4; ++m) acc[m] = fmaf(Tt[(bh+m)*64 + nn], wv, acc[m]);
        }
    }
    #pragma unroll
    for (int m = 0; m < 4; ++m)
        part[ks*32768 + (bt*8 + bh + m)*128 + a] = acc[m];
}

__global__ __launch_bounds__(256) void k_red(const float* __restrict__ part,
                                             float* __restrict__ out)
{
    int i = blockIdx.x*256 + threadIdx.x;
    float s = 0.f;
    #pragma unroll
    for (int ks = 0; ks < 8; ++ks) s += part[ks*32768 + i];
    out[i] = s;
}

extern "C" void kernel_launch(void* const* d_in, const int* in_sizes, int n_in,
                              void* d_out, int out_size, void* d_ws, size_t ws_size,
                              hipStream_t stream)
{
    (void)in_sizes; (void)n_in; (void)out_size; (void)ws_size;
    const float* obs = (const float*)d_in[0];
    const float* w1  = (const float*)d_in[1];
    const float* w2  = (const float*)d_in[2];
    const float* wO  = (const float*)d_in[3];
    const float* c1w = (const float*)d_in[4];
    const float* c1b = (const float*)d_in[5];
    const float* c2w = (const float*)d_in[6];
    const float* c2b = (const float*)d_in[7];
    double* M = (double*)d_ws;
    float* part = (float*)((char*)d_ws + 33554432);

    k_feat<<<dim3(16384), dim3(256), 0, stream>>>(obs, c1w, c1b, c2w, c2b, M);
    k_svd <<<dim3(256),   dim3(512), 0, stream>>>(w1, w2, M);
    k_out <<<dim3(256),   dim3(256), 0, stream>>>((const char*)d_ws, wO, part);
    k_red <<<dim3(128),   dim3(256), 0, stream>>>(part, (float*)d_out);
}